// Round 4
// baseline (3714.181 us; speedup 1.0000x reference)
//
#include <hip/hip_runtime.h>
#include <hip/hip_bf16.h>

#define NB 8
#define NC 128
#define NT 4096
#define NS 1024

// ---------------------------------------------------------------------------
// K/V projection from source. V: float2 v[(b*NS+m)*NC+d].
// K: planar TRANSPOSED  Kr[(b*NC+d)*NS+m], Ki[...]  (coalesced over m later).
// ---------------------------------------------------------------------------
__global__ __launch_bounds__(256) void proj_kv_kernel(
    const float* __restrict__ sr_g, const float* __restrict__ si_g,
    const float* __restrict__ Wkr, const float* __restrict__ Wki,
    const float* __restrict__ bkr, const float* __restrict__ bki,
    const float* __restrict__ Wvr, const float* __restrict__ Wvi,
    const float* __restrict__ bvr, const float* __restrict__ bvi,
    float* __restrict__ Kr, float* __restrict__ Ki, float2* __restrict__ vout)
{
    __shared__ float sr[NC * 32];
    __shared__ float si[NC * 32];
    const int b   = blockIdx.x >> 5;          // 32 tiles of 32 rows
    const int m0  = (blockIdx.x & 31) * 32;
    const int tid = threadIdx.x;

    for (int i = tid; i < NC * 32; i += 256) {
        const int c = i >> 5, m = i & 31;
        const int gi = (b * NC + c) * NS + m0 + m;
        sr[i] = sr_g[gi];
        si[i] = si_g[gi];
    }
    __syncthreads();

    // ---- V: d in lanes (coalesced float2 stores) ----
    {
        const int dl = tid & 31, mg = tid >> 5;
        for (int dk = 0; dk < 4; ++dk) {
            const int d = dk * 32 + dl;
            for (int mm = 0; mm < 4; ++mm) {
                const int m = mg * 4 + mm;
                float ar = 0.f, ai = 0.f;
                #pragma unroll 4
                for (int c = 0; c < NC; ++c) {
                    const float xr = sr[c * 32 + m], xi = si[c * 32 + m];
                    const float wr = Wvr[d * NC + c], wi = Wvi[d * NC + c];
                    ar = fmaf(xr, wr, ar); ar = fmaf(-xi, wi, ar);
                    ai = fmaf(xr, wi, ai); ai = fmaf(xi, wr, ai);
                }
                vout[(b * NS + m0 + m) * NC + d] = make_float2(ar + bvr[d], ai + bvi[d]);
            }
        }
    }
    // ---- K: m in lanes (coalesced planar stores, transposed) ----
    {
        const int ml = tid & 31, dg = tid >> 5;
        for (int dd = 0; dd < 16; ++dd) {
            const int d = dg * 16 + dd;
            float ar = 0.f, ai = 0.f;
            #pragma unroll 4
            for (int c = 0; c < NC; ++c) {
                const float xr = sr[c * 32 + ml], xi = si[c * 32 + ml];
                const float wr = Wkr[d * NC + c], wi = Wki[d * NC + c];
                ar = fmaf(xr, wr, ar); ar = fmaf(-xi, wi, ar);
                ai = fmaf(xr, wi, ai); ai = fmaf(xi, wr, ai);
            }
            Kr[(b * NC + d) * NS + m0 + ml] = ar + bkr[d];
            Ki[(b * NC + d) * NS + m0 + ml] = ai + bki[d];
        }
    }
}

// ---------------------------------------------------------------------------
// Attention: per block = 8 target rows x all 1024 source positions.
// Q computed INLINE. scores in registers (32/thread), softmax via shfl,
// weights -> LDS (union with K-chunk buffer), then out = w @ V.
// Output: FLOAT32. mode 0 = real part at [B][C][Ht][Wt];
//         mode 1 = interleaved (re,im) float pairs (hedge, out_size==2*plane)
// ---------------------------------------------------------------------------
__global__ __launch_bounds__(256) void attn_kernel(
    const float* __restrict__ tr_g, const float* __restrict__ ti_g,
    const float* __restrict__ Wqr, const float* __restrict__ Wqi,
    const float* __restrict__ bqr, const float* __restrict__ bqi,
    const float* __restrict__ Krg, const float* __restrict__ Kig,
    const float2* __restrict__ vin,
    const float* __restrict__ gamma_p, float* __restrict__ out,
    const int mode)
{
    __shared__ float  trs[NC * 8];   // 4 KB : target tile (real)
    __shared__ float  tis[NC * 8];   // 4 KB : target tile (imag)
    __shared__ float2 Qs[8 * NC];    // 8 KB : Q tile
    __shared__ float2 U2[NC * 32];   // 32 KB: K chunk / later w[8][NS]
    __shared__ float2 Vs[16 * NC];   // 16 KB: V chunk
    float* wbuf = reinterpret_cast<float*>(U2);

    const int b   = blockIdx.x >> 9;         // 512 tiles of 8 rows per batch
    const int t0  = (blockIdx.x & 511) * 8;
    const int tid = threadIdx.x;

    // ---- stage target tile: trs[c*8+n] = target[b][c][t0+n] ----
    for (int i = tid; i < NC * 8; i += 256) {
        const int c = i >> 3, n = i & 7;
        const int gi = (b * NC + c) * NT + t0 + n;
        trs[i] = tr_g[gi];
        tis[i] = ti_g[gi];
    }
    __syncthreads();

    const int qr = tid >> 5;   // q-row 0..7
    const int ml = tid & 31;   // lane within row-group

    // ---- inline Q projection: Qs[q][d] = ((t @ Wq^T)+bq)/sqrt(C) ----
    {
        const float inv_s = 0.08838834764831845f; // 1/sqrt(128)
        const float4* W4r = reinterpret_cast<const float4*>(Wqr);
        const float4* W4i = reinterpret_cast<const float4*>(Wqi);
        #pragma unroll
        for (int k = 0; k < 4; ++k) {
            const int d = k * 32 + ml;
            float ar = 0.f, ai = 0.f;
            for (int c4 = 0; c4 < 32; ++c4) {
                const float4 wr4 = W4r[d * 32 + c4];
                const float4 wi4 = W4i[d * 32 + c4];
                const float* wr = &wr4.x;
                const float* wi = &wi4.x;
                #pragma unroll
                for (int e = 0; e < 4; ++e) {
                    const int c = c4 * 4 + e;
                    const float xr = trs[c * 8 + qr];
                    const float xi = tis[c * 8 + qr];
                    ar = fmaf(xr, wr[e], ar); ar = fmaf(-xi, wi[e], ar);
                    ai = fmaf(xr, wi[e], ai); ai = fmaf(xi, wr[e], ai);
                }
            }
            Qs[qr * NC + d] = make_float2((ar + bqr[d]) * inv_s,
                                          (ai + bqi[d]) * inv_s);
        }
    }

    // ---- Phase B: scores. sc[j] = score for m = j*32 + ml ----
    float sc[32];
    #pragma unroll
    for (int j = 0; j < 32; ++j) {
        const int m0 = j * 32;
        __syncthreads();
        for (int i = tid; i < NC * 32; i += 256) {
            const int d = i >> 5, mm = i & 31;
            const int gi = (b * NC + d) * NS + m0 + mm;
            U2[i] = make_float2(Krg[gi], Kig[gi]);
        }
        __syncthreads();
        float acc = 0.f;
        const int qbase = qr * NC;
        #pragma unroll 8
        for (int d = 0; d < NC; ++d) {
            const float2 qv = Qs[qbase + d];
            const float2 kv = U2[d * 32 + ml];
            acc = fmaf(qv.x, kv.x, acc);       // Re(Q conj(K)) = QrKr + QiKi
            acc = fmaf(qv.y, kv.y, acc);
        }
        sc[j] = acc;
    }

    // ---- softmax across 1024 = 32 regs x 32 lanes ----
    float mx = -1e30f;
    #pragma unroll
    for (int j = 0; j < 32; ++j) mx = fmaxf(mx, sc[j]);
    #pragma unroll
    for (int off = 16; off >= 1; off >>= 1)
        mx = fmaxf(mx, __shfl_xor(mx, off, 32));
    float ssum = 0.f;
    #pragma unroll
    for (int j = 0; j < 32; ++j) { sc[j] = __expf(sc[j] - mx); ssum += sc[j]; }
    #pragma unroll
    for (int off = 16; off >= 1; off >>= 1)
        ssum += __shfl_xor(ssum, off, 32);
    const float inv = 1.f / ssum;

    __syncthreads();
    #pragma unroll
    for (int j = 0; j < 32; ++j)
        wbuf[qr * NS + j * 32 + ml] = sc[j] * inv;

    // ---- Phase C: out[q][d] = sum_m w * V ----
    const int dl = tid & 31;
    const int qq = tid >> 5;
    float or_[4] = {0.f, 0.f, 0.f, 0.f};
    float oi_[4] = {0.f, 0.f, 0.f, 0.f};
    for (int mc = 0; mc < NS; mc += 16) {
        __syncthreads();
        for (int i = tid; i < 16 * NC; i += 256) {
            const int mm = i >> 7, d = i & 127;
            Vs[i] = vin[(b * NS + mc + mm) * NC + d];
        }
        __syncthreads();
        #pragma unroll
        for (int mm = 0; mm < 16; ++mm) {
            const float wv = wbuf[qq * NS + mc + mm];
            #pragma unroll
            for (int k = 0; k < 4; ++k) {
                const float2 vv = Vs[mm * NC + k * 32 + dl];
                or_[k] = fmaf(wv, vv.x, or_[k]);
                oi_[k] = fmaf(wv, vv.y, oi_[k]);
            }
        }
    }

    // ---- write FLOAT32 output ----
    const float g = gamma_p[0];
    const int n = t0 + qq;
    #pragma unroll
    for (int k = 0; k < 4; ++k) {
        const int d = k * 32 + dl;
        const size_t base = (size_t)(b * NC + d) * NT + n;
        if (mode == 1) {                       // interleaved complex pairs (hedge)
            reinterpret_cast<float2*>(out)[base] = make_float2(g * or_[k], g * oi_[k]);
        } else {                               // REAL PART, [B][C][Ht][Wt] f32
            out[base] = g * or_[k];
        }
    }
}

// ---------------------------------------------------------------------------
extern "C" void kernel_launch(void* const* d_in, const int* in_sizes, int n_in,
                              void* d_out, int out_size, void* d_ws, size_t ws_size,
                              hipStream_t stream)
{
    const float* target_r = (const float*)d_in[0];
    const float* target_i = (const float*)d_in[1];
    const float* source_r = (const float*)d_in[2];
    const float* source_i = (const float*)d_in[3];
    const float* Wq_r = (const float*)d_in[4];
    const float* Wq_i = (const float*)d_in[5];
    const float* bq_r = (const float*)d_in[6];
    const float* bq_i = (const float*)d_in[7];
    const float* Wk_r = (const float*)d_in[8];
    const float* Wk_i = (const float*)d_in[9];
    const float* bk_r = (const float*)d_in[10];
    const float* bk_i = (const float*)d_in[11];
    const float* Wv_r = (const float*)d_in[12];
    const float* Wv_i = (const float*)d_in[13];
    const float* bv_r = (const float*)d_in[14];
    const float* bv_i = (const float*)d_in[15];
    const float* gamma = (const float*)d_in[16];

    // workspace (floats): Kr 1.05M | Ki 1.05M | V 1.05M float2  => 16.8 MB
    float*  ws   = (float*)d_ws;
    float*  Kr   = ws;
    float*  Ki   = Kr + (size_t)NB * NC * NS;
    float2* vbuf = (float2*)(Ki + (size_t)NB * NC * NS);

    proj_kv_kernel<<<NB * (NS / 32), 256, 0, stream>>>(
        source_r, source_i, Wk_r, Wk_i, bk_r, bk_i,
        Wv_r, Wv_i, bv_r, bv_i, Kr, Ki, vbuf);

    // mode: 0 = real-part f32 (out_size == B*C*Ht*Wt), 1 = interleaved complex f32
    const size_t plane = (size_t)NB * NC * NT;
    const int mode = (out_size == (int)(2 * plane)) ? 1 : 0;

    attn_kernel<<<NB * (NT / 8), 256, 0, stream>>>(
        target_r, target_i, Wq_r, Wq_i, bq_r, bq_i,
        Kr, Ki, vbuf, gamma, (float*)d_out, mode);
}

// Round 7
// 258.467 us; speedup vs baseline: 14.3701x; 14.3701x over previous
//
#include <hip/hip_runtime.h>
#include <hip/hip_bf16.h>

#define NB 8
#define NC 128
#define NT 4096
#define NS 1024

typedef short bf16x8 __attribute__((ext_vector_type(8)));
typedef float f32x4  __attribute__((ext_vector_type(4)));

#define MFMA16(a, b, c) __builtin_amdgcn_mfma_f32_16x16x32_bf16(a, b, c, 0, 0, 0)

__device__ __forceinline__ short f2b(float x) {
    __hip_bfloat16 h = __float2bfloat16(x);
    return *reinterpret_cast<short*>(&h);
}

// ---------------------------------------------------------------------------
// Pack complex weights into doubled-K (256) bf16 matrices, row = out col d',
// col = k.  Q/K: [256][256]: rows<128 (real out): [Wr | -Wi]; rows>=128 (imag
// out): [Wi | Wr].  V (real out only): [128][256] = [Wvr | -Wvi].
// ---------------------------------------------------------------------------
__global__ __launch_bounds__(256) void pack_w_kernel(
    const float* __restrict__ Wqr, const float* __restrict__ Wqi,
    const float* __restrict__ Wkr, const float* __restrict__ Wki,
    const float* __restrict__ Wvr, const float* __restrict__ Wvi,
    __hip_bfloat16* __restrict__ WqT, __hip_bfloat16* __restrict__ WkT,
    __hip_bfloat16* __restrict__ WvT)
{
    const int idx = blockIdx.x * 256 + threadIdx.x;   // 640 blocks = 163840
    const float *Wr, *Wi; __hip_bfloat16* dst; int base;
    if (idx < 65536)       { Wr = Wqr; Wi = Wqi; dst = WqT; base = idx; }
    else if (idx < 131072) { Wr = Wkr; Wi = Wki; dst = WkT; base = idx - 65536; }
    else                   { Wr = Wvr; Wi = Wvi; dst = WvT; base = idx - 131072; }
    const int dp = base >> 8, k = base & 255;
    const int d  = dp & 127;
    float v;
    if (dp < 128) v = (k < 128) ? Wr[d * 128 + k] : -Wi[d * 128 + k - 128];
    else          v = (k < 128) ? Wi[d * 128 + k] :  Wr[d * 128 + k - 128];
    dst[base] = __float2bfloat16(v);
}

// ---------------------------------------------------------------------------
// K projection GEMM: A[NS x 256] (= [sr|si] from [C][NS] input, cast bf16)
// times WT rows -> Kh [B*NS][256] bf16, bias epilogue.
// ---------------------------------------------------------------------------
__global__ __launch_bounds__(256) void proj256_kernel(
    const float* __restrict__ Xr, const float* __restrict__ Xi,
    const __hip_bfloat16* __restrict__ WT,
    const float* __restrict__ br, const float* __restrict__ bi,
    __hip_bfloat16* __restrict__ outp)
{
    __shared__ __align__(16) char smem[64 * 528];     // As[64][264] bf16
    const int nblk = NS >> 6;
    const int b    = blockIdx.x / nblk;
    const int n0   = (blockIdx.x % nblk) * 64;
    const int tid  = threadIdx.x;

    for (int i = tid; i < 64 * 64; i += 256) {
        const int cp = i >> 6, n = i & 63, c = cp * 2;
        const size_t rb = (size_t)(b * NC + c) * NS + n0 + n;
        const unsigned pr = (unsigned short)f2b(Xr[rb]) |
                            ((unsigned)(unsigned short)f2b(Xr[rb + NS]) << 16);
        const unsigned pi = (unsigned short)f2b(Xi[rb]) |
                            ((unsigned)(unsigned short)f2b(Xi[rb + NS]) << 16);
        *(unsigned*)(smem + n * 528 + c * 2)         = pr;
        *(unsigned*)(smem + n * 528 + (128 + c) * 2) = pi;
    }
    __syncthreads();

    const int w = tid >> 6, l15 = tid & 15, q = (tid & 63) >> 4;
    const int row0 = w * 16;

    f32x4 acc[16];
    #pragma unroll
    for (int j = 0; j < 16; ++j) { acc[j][0]=0.f; acc[j][1]=0.f; acc[j][2]=0.f; acc[j][3]=0.f; }

    #pragma unroll
    for (int t = 0; t < 8; ++t) {
        const bf16x8 af = *(const bf16x8*)(smem + (row0 + l15) * 528 + (t * 32 + q * 8) * 2);
        #pragma unroll
        for (int j = 0; j < 16; ++j) {
            const int col = j * 16 + l15;
            const bf16x8 bf = *(const bf16x8*)((const char*)WT + col * 512 + (t * 32 + q * 8) * 2);
            acc[j] = MFMA16(af, bf, acc[j]);
        }
    }

    #pragma unroll
    for (int j = 0; j < 16; ++j) {
        const int col  = j * 16 + l15;
        const float bv = (col < 128) ? br[col] : bi[col - 128];
        #pragma unroll
        for (int r = 0; r < 4; ++r) {
            const int n = n0 + row0 + q * 4 + r;
            outp[((size_t)(b * NS + n) << 8) + col] = __float2bfloat16(acc[j][r] + bv);
        }
    }
}

// ---------------------------------------------------------------------------
// V projection (real part only), output TRANSPOSED: VrT[b][d][m] bf16.
// ---------------------------------------------------------------------------
__global__ __launch_bounds__(256) void projV2_kernel(
    const float* __restrict__ Xr, const float* __restrict__ Xi,
    const __hip_bfloat16* __restrict__ WT,   // [128][256]
    const float* __restrict__ br,
    __hip_bfloat16* __restrict__ outp)       // [B][128][NS]
{
    __shared__ __align__(16) char smem[64 * 528];
    const int nblk = NS >> 6;
    const int b    = blockIdx.x / nblk;
    const int n0   = (blockIdx.x % nblk) * 64;
    const int tid  = threadIdx.x;

    for (int i = tid; i < 64 * 64; i += 256) {
        const int cp = i >> 6, n = i & 63, c = cp * 2;
        const size_t rb = (size_t)(b * NC + c) * NS + n0 + n;
        const unsigned pr = (unsigned short)f2b(Xr[rb]) |
                            ((unsigned)(unsigned short)f2b(Xr[rb + NS]) << 16);
        const unsigned pi = (unsigned short)f2b(Xi[rb]) |
                            ((unsigned)(unsigned short)f2b(Xi[rb + NS]) << 16);
        *(unsigned*)(smem + n * 528 + c * 2)         = pr;
        *(unsigned*)(smem + n * 528 + (128 + c) * 2) = pi;
    }
    __syncthreads();

    const int w = tid >> 6, l15 = tid & 15, q = (tid & 63) >> 4;
    const int row0 = w * 16;

    f32x4 acc[8];
    #pragma unroll
    for (int j = 0; j < 8; ++j) { acc[j][0]=0.f; acc[j][1]=0.f; acc[j][2]=0.f; acc[j][3]=0.f; }

    #pragma unroll
    for (int t = 0; t < 8; ++t) {
        const bf16x8 af = *(const bf16x8*)(smem + (row0 + l15) * 528 + (t * 32 + q * 8) * 2);
        #pragma unroll
        for (int j = 0; j < 8; ++j) {
            const int col = j * 16 + l15;
            const bf16x8 bf = *(const bf16x8*)((const char*)WT + col * 512 + (t * 32 + q * 8) * 2);
            acc[j] = MFMA16(af, bf, acc[j]);
        }
    }
    __syncthreads();                         // done reading As; reuse smem

    #pragma unroll
    for (int j = 0; j < 8; ++j) {
        const int d = j * 16 + l15;
        #pragma unroll
        for (int r = 0; r < 4; ++r) {
            const int m = row0 + q * 4 + r;
            *(__hip_bfloat16*)(smem + d * 144 + m * 2) = __float2bfloat16(acc[j][r] + br[d]);
        }
    }
    __syncthreads();
    for (int i = tid; i < 128 * 8; i += 256) {
        const int d = i >> 3, seg = i & 7;
        const int4 v = *(const int4*)(smem + d * 144 + seg * 16);
        *(int4*)((char*)outp + ((size_t)(b * NC + d) * NS + n0) * 2 + seg * 16) = v;
    }
}

// ---------------------------------------------------------------------------
// Flash attention with INLINE Q projection.  Block = batch b x 64 target rows.
// Wave w owns rows 16w..16w+15; online softmax wave-local in registers.
// ---------------------------------------------------------------------------
__global__ __launch_bounds__(256) void attn_mfma_kernel(
    const float* __restrict__ tr_g, const float* __restrict__ ti_g,
    const __hip_bfloat16* __restrict__ WqT,
    const float* __restrict__ bqr, const float* __restrict__ bqi,
    const __hip_bfloat16* __restrict__ Kh, const __hip_bfloat16* __restrict__ VrT,
    const float* __restrict__ gamma_p, float* __restrict__ out)
{
    __shared__ __align__(16) char smem[61440];
    char* ks = smem;            // 64 x 528B : target tile -> Q-hat -> K chunks
    char* vs = smem + 33792;    // 128 x 144B: VrT chunk [d][k]
    char* ps = smem + 52224;    // 4 waves x 16 x 144B: P, wave-private

    const int b    = blockIdx.x >> 6;
    const int n0   = (blockIdx.x & 63) * 64;
    const int tid  = threadIdx.x;
    const int w    = tid >> 6, l15 = tid & 15, q = (tid & 63) >> 4;
    const int row0 = w * 16;
    char* psw = ps + w * 2304;

    // ---- stage target tile As[n][c] (64 x 256 bf16) into ks ----
    for (int i = tid; i < 64 * 64; i += 256) {
        const int cp = i >> 6, n = i & 63, c = cp * 2;
        const size_t rb = (size_t)(b * NC + c) * NT + n0 + n;
        const unsigned pr = (unsigned short)f2b(tr_g[rb]) |
                            ((unsigned)(unsigned short)f2b(tr_g[rb + NT]) << 16);
        const unsigned pi = (unsigned short)f2b(ti_g[rb]) |
                            ((unsigned)(unsigned short)f2b(ti_g[rb + NT]) << 16);
        *(unsigned*)(ks + n * 528 + c * 2)         = pr;
        *(unsigned*)(ks + n * 528 + (128 + c) * 2) = pi;
    }
    __syncthreads();

    // ---- inline Q projection: rows row0..row0+15 x 256 cols ----
    {
        f32x4 qacc[16];
        #pragma unroll
        for (int j = 0; j < 16; ++j) { qacc[j][0]=0.f; qacc[j][1]=0.f; qacc[j][2]=0.f; qacc[j][3]=0.f; }
        #pragma unroll
        for (int t = 0; t < 8; ++t) {
            const bf16x8 af = *(const bf16x8*)(ks + (row0 + l15) * 528 + (t * 32 + q * 8) * 2);
            #pragma unroll
            for (int j = 0; j < 16; ++j) {
                const int col = j * 16 + l15;
                const bf16x8 bf = *(const bf16x8*)((const char*)WqT + col * 512 + (t * 32 + q * 8) * 2);
                qacc[j] = MFMA16(af, bf, qacc[j]);
            }
        }
        __syncthreads();                     // all waves done reading As
        const float inv_s = 0.08838834764831845f;   // 1/sqrt(128)
        #pragma unroll
        for (int j = 0; j < 16; ++j) {
            const int col  = j * 16 + l15;
            const float bv = (col < 128) ? bqr[col] : bqi[col - 128];
            #pragma unroll
            for (int r = 0; r < 4; ++r) {
                const int row = row0 + q * 4 + r;
                *(__hip_bfloat16*)(ks + row * 528 + col * 2) =
                    __float2bfloat16((qacc[j][r] + bv) * inv_s);
            }
        }
    }
    __syncthreads();

    bf16x8 qf[8];
    #pragma unroll
    for (int t = 0; t < 8; ++t)
        qf[t] = *(const bf16x8*)(ks + (row0 + l15) * 528 + (t * 32 + q * 8) * 2);

    f32x4 oacc[8];
    #pragma unroll
    for (int j = 0; j < 8; ++j) { oacc[j][0]=0.f; oacc[j][1]=0.f; oacc[j][2]=0.f; oacc[j][3]=0.f; }
    float m_run[4] = {-1e30f, -1e30f, -1e30f, -1e30f};
    float l_run[4] = {0.f, 0.f, 0.f, 0.f};

    for (int ch = 0; ch < 16; ++ch) {
        const int s0 = ch * 64;
        __syncthreads();                     // qf in regs / prev chunk done
        {
            // K chunk: 64 rows x 512 B (FULL row: 32 segs of 16 B)
            const char* kb = (const char*)(Kh + ((size_t)(b * NS + s0) << 8));
            for (int i = tid; i < 64 * 32; i += 256) {
                const int m = i >> 5, seg = i & 31;
                *(int4*)(ks + m * 528 + seg * 16) = *(const int4*)(kb + m * 512 + seg * 16);
            }
            const char* vb = (const char*)VrT + ((size_t)b * NC * NS + s0) * 2;
            for (int i = tid; i < 128 * 8; i += 256) {
                const int d = i >> 3, seg = i & 7;
                *(int4*)(vs + d * 144 + seg * 16) = *(const int4*)(vb + (size_t)d * 2048 + seg * 16);
            }
        }
        __syncthreads();

        f32x4 s[4];
        #pragma unroll
        for (int j = 0; j < 4; ++j) { s[j][0]=0.f; s[j][1]=0.f; s[j][2]=0.f; s[j][3]=0.f; }
        #pragma unroll
        for (int t = 0; t < 8; ++t) {
            #pragma unroll
            for (int j = 0; j < 4; ++j) {
                const bf16x8 kf = *(const bf16x8*)(ks + (j * 16 + l15) * 528 + (t * 32 + q * 8) * 2);
                s[j] = MFMA16(qf[t], kf, s[j]);
            }
        }

        float alpha_r[4];
        #pragma unroll
        for (int r = 0; r < 4; ++r) {
            float mx = fmaxf(fmaxf(s[0][r], s[1][r]), fmaxf(s[2][r], s[3][r]));
            #pragma unroll
            for (int off = 8; off >= 1; off >>= 1)
                mx = fmaxf(mx, __shfl_xor(mx, off, 16));
            const float mn = fmaxf(m_run[r], mx);
            const float a  = __expf(m_run[r] - mn);
            m_run[r] = mn; alpha_r[r] = a;
            float sum = 0.f;
            #pragma unroll
            for (int j = 0; j < 4; ++j) {
                const float p = __expf(s[j][r] - mn);
                s[j][r] = p; sum += p;
            }
            #pragma unroll
            for (int off = 8; off >= 1; off >>= 1)
                sum += __shfl_xor(sum, off, 16);
            l_run[r] = l_run[r] * a + sum;
        }

        #pragma unroll
        for (int j = 0; j < 4; ++j) {
            #pragma unroll
            for (int r = 0; r < 4; ++r)
                *(__hip_bfloat16*)(psw + (q * 4 + r) * 144 + (j * 16 + l15) * 2) =
                    __float2bfloat16(s[j][r]);
        }
        __syncthreads();                     // P visible before frag reads

        #pragma unroll
        for (int j = 0; j < 8; ++j) {
            #pragma unroll
            for (int r = 0; r < 4; ++r) oacc[j][r] *= alpha_r[r];
        }
        #pragma unroll
        for (int t2 = 0; t2 < 2; ++t2) {
            const bf16x8 pf = *(const bf16x8*)(psw + l15 * 144 + (t2 * 32 + q * 8) * 2);
            #pragma unroll
            for (int j = 0; j < 8; ++j) {
                const bf16x8 vf = *(const bf16x8*)(vs + (j * 16 + l15) * 144 + (t2 * 32 + q * 8) * 2);
                oacc[j] = MFMA16(pf, vf, oacc[j]);
            }
        }
    }

    __syncthreads();
    float* Of = (float*)smem;                // 128 x 65 f32 (reuse)
    const float g = gamma_p[0];
    #pragma unroll
    for (int r = 0; r < 4; ++r) {
        const float inv_l = g / fmaxf(l_run[r], 1e-30f);
        const int m = row0 + q * 4 + r;
        #pragma unroll
        for (int j = 0; j < 8; ++j)
            Of[(j * 16 + l15) * 65 + m] = oacc[j][r] * inv_l;
    }
    __syncthreads();
    float* ob = out + (size_t)b * NC * NT + n0;
    for (int i = tid; i < 128 * 64; i += 256) {
        const int d = i >> 6, m = i & 63;
        ob[(size_t)d * NT + m] = Of[d * 65 + m];
    }
}

// ---------------------------------------------------------------------------
extern "C" void kernel_launch(void* const* d_in, const int* in_sizes, int n_in,
                              void* d_out, int out_size, void* d_ws, size_t ws_size,
                              hipStream_t stream)
{
    const float* target_r = (const float*)d_in[0];
    const float* target_i = (const float*)d_in[1];
    const float* source_r = (const float*)d_in[2];
    const float* source_i = (const float*)d_in[3];
    const float* Wq_r = (const float*)d_in[4];
    const float* Wq_i = (const float*)d_in[5];
    const float* bq_r = (const float*)d_in[6];
    const float* bq_i = (const float*)d_in[7];
    const float* Wk_r = (const float*)d_in[8];
    const float* Wk_i = (const float*)d_in[9];
    const float* bk_r = (const float*)d_in[10];
    const float* bk_i = (const float*)d_in[11];
    const float* Wv_r = (const float*)d_in[12];
    const float* Wv_i = (const float*)d_in[13];
    const float* bv_r = (const float*)d_in[14];
    const float* bv_i = (const float*)d_in[15];
    const float* gamma = (const float*)d_in[16];

    // workspace carve (bytes) — total 6.62 MB
    char* ws = (char*)d_ws;
    __hip_bfloat16* Kh  = (__hip_bfloat16*)(ws);                    // 4,194,304
    __hip_bfloat16* VrT = (__hip_bfloat16*)(ws + 4194304);          // 2,097,152
    __hip_bfloat16* WqT = (__hip_bfloat16*)(ws + 6291456);          //   131,072
    __hip_bfloat16* WkT = (__hip_bfloat16*)(ws + 6422528);          //   131,072
    __hip_bfloat16* WvT = (__hip_bfloat16*)(ws + 6553600);          //    65,536

    pack_w_kernel<<<640, 256, 0, stream>>>(Wq_r, Wq_i, Wk_r, Wk_i, Wv_r, Wv_i,
                                           WqT, WkT, WvT);

    proj256_kernel<<<NB * (NS / 64), 256, 0, stream>>>(
        source_r, source_i, WkT, bk_r, bk_i, Kh);
    projV2_kernel<<<NB * (NS / 64), 256, 0, stream>>>(
        source_r, source_i, WvT, bv_r, VrT);

    attn_mfma_kernel<<<NB * (NT / 64), 256, 0, stream>>>(
        target_r, target_i, WqT, bq_r, bq_i, Kh, VrT, gamma, (float*)d_out);
}